// Round 16
// baseline (5136.234 us; speedup 1.0000x reference)
//
#include <hip/hip_runtime.h>
#include <hip/hip_bf16.h>
#include <cstdint>
#include <cstddef>
#include <math.h>

using bf16 = __hip_bfloat16;
typedef __bf16 bf16x8 __attribute__((ext_vector_type(8)));
typedef float f32x4 __attribute__((ext_vector_type(4)));

// ---------------- constants ----------------
static constexpr int NHEAD = 12;
static constexpr int NTOK  = 211;   // 210 patches + cls
static constexpr int DEPTH = 11;

// ---------------- global->LDS direct load ----------------
static __device__ __forceinline__ void gload_lds16(const bf16* g, bf16* lds) {
  __builtin_amdgcn_global_load_lds(
      (const __attribute__((address_space(1))) uint32_t*)g,
      (__attribute__((address_space(3))) uint32_t*)lds,
      16, 0, 0);
}

__device__ __forceinline__ float gelu_f(float x) {
  float u = x * (0.7978845608f + 0.0356774081f * x * x);
  float t = 1.f - 2.f / (__expf(2.f * u) + 1.f);
  return 0.5f * x * (1.f + t);
}

static __device__ __forceinline__ unsigned short bf16_bits(float x) {
  return __builtin_bit_cast(unsigned short, __float2bfloat16(x));
}

// b2 shuffle: gathered row -> source row index within its batch's tA sequence
static __device__ __forceinline__ int b2src(int row) {
  int bb = row / 53, jj = row - bb * 53;
  int i = bb >> 6, b = bb & 63;
  int src;
  if (jj == 0) src = 0;
  else {
    int jx = i * 52 + (jj - 1);
    int mm = (jx & 1) * 105 + (jx >> 1);
    src = (mm < 206) ? (5 + mm) : (1 + (mm - 206));
  }
  return b * 211 + src;
}

// ---------------- m97-style double-buffered TN GEMM, 128x128 tile, 16x16x32 MFMA ----------------
// (round-9/13 verified: 111us fc1-class, bank conflicts 0.)
// OUT=0: C[r*sC+col] = A@Bt + bias (+gelu, +res[r*sR+col]); CT f32 or bf16.
//   f32 path: two-half LDS-bounce epilogue -> float4 res loads + float4 stores.
// OUT=2: qkv-split epilogue -> head-blocked Q/K/V [(bb*12+h)][pad][64].
template <bool GELU, bool RES, typename CT, int OUT>
__global__ __launch_bounds__(256) void gemm_db(
    const bf16* __restrict__ A, const bf16* __restrict__ Bt,
    const float* __restrict__ bias, const float* __restrict__ res,
    CT* __restrict__ C, int M, int N, int K, int gn, int sA, int sR, int sC,
    bf16* __restrict__ qh, bf16* __restrict__ kh, bf16* __restrict__ vh,
    int pad, int ntd, int coff)
{
  __shared__ bf16 sb[2][8192];   // 32 KB total

  const int tid = threadIdx.x;
  const int w = tid >> 6, l = tid & 63;
  const int lr = l & 15, lg = l >> 4;
  const int wr = (w >> 1) * 64, wc = (w & 1) * 64;

  const int nwg = gridDim.x, lin = blockIdx.x;
  const int q = nwg >> 3, r = nwg & 7;
  const int xcd = lin & 7, pos = lin >> 3;
  const int wg = (xcd < r ? xcd * (q + 1) : r * (q + 1) + (xcd - r) * q) + pos;
  const int bm0 = (wg / gn) * 128, bn0 = (wg % gn) * 128;

  f32x4 acc[4][4];
#pragma unroll
  for (int i = 0; i < 4; ++i)
#pragma unroll
    for (int j = 0; j < 4; ++j) acc[i][j] = f32x4{0.f, 0.f, 0.f, 0.f};

  size_t aof[2], bof[2]; int dst[2];
#pragma unroll
  for (int j = 0; j < 2; ++j) {
    const int c = j * 256 + tid;
    const int row = c >> 2;
    const int ch = (c & 3) ^ ((row >> 1) & 3);
    int ar = bm0 + row; if (ar >= M) ar = M - 1;
    aof[j] = (size_t)ar * sA + ch * 8;
    bof[j] = (size_t)(bn0 + row) * K + ch * 8;
    dst[j] = c * 8;
  }

  const int nt = K >> 5;

  auto stage = [&](int t) {
    bf16* s = sb[t & 1];
    const size_t ko = (size_t)t * 32;
    gload_lds16(A + aof[0] + ko, s + dst[0]);
    gload_lds16(A + aof[1] + ko, s + dst[1]);
    gload_lds16(Bt + bof[0] + ko, s + 4096 + dst[0]);
    gload_lds16(Bt + bof[1] + ko, s + 4096 + dst[1]);
  };

  stage(0);
  __syncthreads();

  const int swz = (lg ^ ((lr >> 1) & 3)) * 8;

  for (int t = 0; t < nt; ++t) {
    if (t + 1 < nt) stage(t + 1);
    const bf16* As = sb[t & 1];
    const bf16* Bs = As + 4096;
    bf16x8 af[4], bv[4];
#pragma unroll
    for (int mi = 0; mi < 4; ++mi)
      af[mi] = *(const bf16x8*)(As + (wr + mi * 16 + lr) * 32 + swz);
#pragma unroll
    for (int ni = 0; ni < 4; ++ni)
      bv[ni] = *(const bf16x8*)(Bs + (wc + ni * 16 + lr) * 32 + swz);
#pragma unroll
    for (int mi = 0; mi < 4; ++mi)
#pragma unroll
      for (int ni = 0; ni < 4; ++ni)
        acc[mi][ni] = __builtin_amdgcn_mfma_f32_16x16x32_bf16(af[mi], bv[ni], acc[mi][ni], 0, 0, 0);
    __syncthreads();
  }

  if constexpr (OUT == 2 || sizeof(CT) == 2) {
    // ---- bf16/qkv out: LDS-bounce (bank-spread XOR), then 16B vector stores ----
    char* lb = (char*)sb;     // 32 KB = 128 rows x 256 B
#pragma unroll
    for (int mi = 0; mi < 4; ++mi) {
#pragma unroll
      for (int ni = 0; ni < 4; ++ni) {
        const int cloc = wc + ni * 16 + lr;
        const float bvl = bias[bn0 + cloc];
#pragma unroll
        for (int r2 = 0; r2 < 4; ++r2) {
          const int rowl = wr + mi * 16 + lg * 4 + r2;
          float v = acc[mi][ni][r2] + bvl;
          if constexpr (GELU) v = gelu_f(v);
          *(unsigned short*)(lb + rowl * 256 + ((cloc * 2) ^ (((rowl >> 1) & 6) << 4))) =
              bf16_bits(v);
        }
      }
    }
    __syncthreads();
#pragma unroll
    for (int j = 0; j < 8; ++j) {
      const int flat = j * 256 + tid;
      const int row = flat >> 4, ch = flat & 15;
      const int grow = bm0 + row;
      if (grow < M) {
        const f32x4 v = *(const f32x4*)(lb + row * 256 + ((ch * 16) ^ (((row >> 1) & 6) << 4)));
        if constexpr (OUT == 2) {
          const int col0 = bn0 + ch * 8 + coff;
          const int region = (col0 >= 1536) ? 2 : (col0 >= 768 ? 1 : 0);
          const int c7 = col0 - region * 768;
          const int h = c7 >> 6, d = c7 & 63;
          const int bb2 = grow / ntd;
          const int tok = grow - bb2 * ntd;
          bf16* db = (region == 0) ? qh : ((region == 1) ? kh : vh);
          *(f32x4*)((char*)db + (((size_t)(bb2 * 12 + h) * pad + tok) * 64 + d) * 2) = v;
        } else {
          *(f32x4*)((char*)C + ((size_t)grow * sC + bn0 + ch * 8) * 2) = v;
        }
      }
    }
  } else {
    // ---- f32 out: two-half LDS bounce -> float4 res + float4 stores ----
    float* lb4 = (float*)sb;   // [128][64] f32 per half (exactly 32 KB)
#pragma unroll
    for (int hh = 0; hh < 2; ++hh) {
      if ((w & 1) == hh) {
#pragma unroll
        for (int mi = 0; mi < 4; ++mi) {
#pragma unroll
          for (int ni = 0; ni < 4; ++ni) {
            const int c64 = ni * 16 + lr;
            const float bvl = bias[bn0 + hh * 64 + c64];
#pragma unroll
            for (int r2 = 0; r2 < 4; ++r2) {
              const int rowl = wr + mi * 16 + lg * 4 + r2;
              float v = acc[mi][ni][r2] + bvl;
              if constexpr (GELU) v = gelu_f(v);
              lb4[rowl * 64 + c64] = v;
            }
          }
        }
      }
      __syncthreads();
#pragma unroll
      for (int j = 0; j < 8; ++j) {
        const int flat = j * 256 + tid;
        const int row = flat >> 4, cc = flat & 15;
        const int grow = bm0 + row;
        if (grow < M) {
          f32x4 v = *(const f32x4*)(lb4 + row * 64 + cc * 4);
          const int col0 = bn0 + hh * 64 + cc * 4;
          if constexpr (RES) {
            v += *(const f32x4*)(res + (size_t)grow * sR + col0);
          }
          *(f32x4*)((float*)C + (size_t)grow * sC + col0) = v;
        }
      }
      __syncthreads();
    }
  }
}

// ---------------- V transpose (head path only): vcomp[bbh][tok][64] -> vT[bbh][d][pad] ----------------
__global__ __launch_bounds__(256) void vtrans_kernel(
    const bf16* __restrict__ vcomp, bf16* __restrict__ vT, int ntok, int pad)
{
  __shared__ unsigned short t[224 * 65];
  const int bb = blockIdx.x, h = blockIdx.y;
  const unsigned short* src = (const unsigned short*)vcomp + (size_t)(bb * 12 + h) * pad * 64;
  for (int idx = threadIdx.x; idx < ntok * 64; idx += 256) {
    int tok = idx >> 6, d = idx & 63;
    t[tok * 65 + d] = src[idx];
  }
  __syncthreads();
  unsigned short* dstp = (unsigned short*)vT + (size_t)(bb * 12 + h) * 64 * pad;
  for (int idx = threadIdx.x; idx < 64 * ntok; idx += 256) {
    int d = idx / ntok, tok = idx - d * ntok;
    dstp[(size_t)d * pad + tok] = t[tok * 65 + d];
  }
}

// ---------------- fused attention: one block per (bb, head); head-blocked Q/K ----------------
template <int NKF, bool ONLY0>
__global__ __launch_bounds__(256) void attn_kernel(
    const bf16* __restrict__ qb, const bf16* __restrict__ kb,
    const bf16* __restrict__ vsrc, bf16* __restrict__ ao, int ntok, int pad)
{
  constexpr int NPAD = NKF * 16;
  constexpr int VST = NPAD + 8;       // Vt row stride (elems); 16B aligned
  __shared__ bf16 Pl[4][16][NPAD];
  __shared__ __bf16 Vt[ONLY0 ? 1 : 64][ONLY0 ? 1 : VST];
  const int bb = blockIdx.x;
  const int h = blockIdx.y;
  const int tid = threadIdx.x;
  const int w = tid >> 6, l = tid & 63;
  const int lr = l & 15, lg = l >> 4;
  const int bbh = bb * 12 + h;
  const __bf16* qbase = reinterpret_cast<const __bf16*>(qb) + (size_t)bbh * pad * 64;
  const __bf16* kbase = reinterpret_cast<const __bf16*>(kb) + (size_t)bbh * pad * 64;
  const __bf16* vglob = reinterpret_cast<const __bf16*>(vsrc) +
                        (ONLY0 ? (size_t)bbh * 64 * pad : (size_t)bbh * pad * 64);

  if constexpr (!ONLY0) {
    for (int idx = tid; idx < ntok * 64; idx += 256) {
      const int tok = idx >> 6, d = idx & 63;
      Vt[d][tok] = vglob[idx];
    }
    __syncthreads();
  }
  if (ONLY0 && w > 0) return;   // 1-wave head path; no barrier below

  for (int qt = w; qt < (ONLY0 ? 1 : NKF); qt += 4) {
    int qrow = qt * 16 + lr; if (qrow >= ntok) qrow = ntok - 1;
    const __bf16* qp = qbase + qrow * 64 + lg * 8;
    const bf16x8 qf0 = *reinterpret_cast<const bf16x8*>(qp);
    const bf16x8 qf1 = *reinterpret_cast<const bf16x8*>(qp + 32);

    f32x4 s[NKF];
#pragma unroll
    for (int kf = 0; kf < NKF; ++kf) {
      int krow = kf * 16 + lr; if (krow >= ntok) krow = ntok - 1;
      const __bf16* kp = kbase + krow * 64 + lg * 8;
      f32x4 a = f32x4{0.f, 0.f, 0.f, 0.f};
      a = __builtin_amdgcn_mfma_f32_16x16x32_bf16(qf0, *reinterpret_cast<const bf16x8*>(kp), a, 0, 0, 0);
      a = __builtin_amdgcn_mfma_f32_16x16x32_bf16(qf1, *reinterpret_cast<const bf16x8*>(kp + 32), a, 0, 0, 0);
      s[kf] = a;
    }

    float rs[4];
#pragma unroll
    for (int r = 0; r < 4; ++r) {
      float mx = -1e30f;
#pragma unroll
      for (int kf = 0; kf < NKF; ++kf)
        if (kf * 16 + lr < ntok) mx = fmaxf(mx, s[kf][r]);
#pragma unroll
      for (int d = 1; d < 16; d <<= 1) mx = fmaxf(mx, __shfl_xor(mx, d));
      float sum = 0.f;
#pragma unroll
      for (int kf = 0; kf < NKF; ++kf) {
        float p = 0.f;
        if (kf * 16 + lr < ntok) p = __expf((s[kf][r] - mx) * 0.125f);
        sum += p;
        Pl[w][lg * 4 + r][kf * 16 + lr] = __float2bfloat16(p);
      }
#pragma unroll
      for (int d = 1; d < 16; d <<= 1) sum += __shfl_xor(sum, d);
      rs[r] = sum;
    }
    __builtin_amdgcn_s_waitcnt(0);  // lgkm: Pl writes visible to this wave

    f32x4 o[4];
#pragma unroll
    for (int ni = 0; ni < 4; ++ni) o[ni] = f32x4{0.f, 0.f, 0.f, 0.f};
#pragma unroll
    for (int ks = 0; ks < NPAD / 32; ++ks) {
      const bf16x8 pa = *reinterpret_cast<const bf16x8*>(&Pl[w][lr][ks * 32 + lg * 8]);
#pragma unroll
      for (int ni = 0; ni < 4; ++ni) {
        bf16x8 vb;
        if constexpr (ONLY0) {
          vb = *reinterpret_cast<const bf16x8*>(
              vglob + (size_t)(ni * 16 + lr) * pad + ks * 32 + lg * 8);
        } else {
          vb = *reinterpret_cast<const bf16x8*>(&Vt[ni * 16 + lr][ks * 32 + lg * 8]);
        }
        o[ni] = __builtin_amdgcn_mfma_f32_16x16x32_bf16(pa, vb, o[ni], 0, 0, 0);
      }
    }
#pragma unroll
    for (int ni = 0; ni < 4; ++ni)
#pragma unroll
      for (int r = 0; r < 4; ++r) {
        int qq = qt * 16 + lg * 4 + r;
        if (qq < (ONLY0 ? 1 : ntok)) {
          float val = o[ni][r] / rs[r];
          ao[((size_t)bb * ntok + qq) * 768 + h * 64 + ni * 16 + lr] = __float2bfloat16(val);
        }
      }
  }
}

// ---------------- layernorm body (device), explicit source row pointer ----------------
static __device__ __forceinline__ void ln_row2(
    const float* __restrict__ xrow, const float* __restrict__ g, const float* __restrict__ b,
    bf16* __restrict__ outrow, int l)
{
  const float4* xr = reinterpret_cast<const float4*>(xrow);
  float4 v[3]; float s = 0.f;
#pragma unroll
  for (int i = 0; i < 3; ++i) {
    v[i] = xr[l + i * 64];
    s += v[i].x + v[i].y + v[i].z + v[i].w;
  }
#pragma unroll
  for (int d = 1; d < 64; d <<= 1) s += __shfl_xor(s, d);
  float mean = s * (1.f / 768.f);
  float s2 = 0.f;
#pragma unroll
  for (int i = 0; i < 3; ++i) {
    float a0 = v[i].x - mean, a1 = v[i].y - mean, a2 = v[i].z - mean, a3 = v[i].w - mean;
    s2 += a0 * a0 + a1 * a1 + a2 * a2 + a3 * a3;
  }
#pragma unroll
  for (int d = 1; d < 64; d <<= 1) s2 += __shfl_xor(s2, d);
  float rstd = rsqrtf(s2 * (1.f / 768.f) + 1e-6f);
  const float4* g4 = reinterpret_cast<const float4*>(g);
  const float4* b4 = reinterpret_cast<const float4*>(b);
  unsigned short* orow = reinterpret_cast<unsigned short*>(outrow);
#pragma unroll
  for (int i = 0; i < 3; ++i) {
    float4 gg = g4[l + i * 64], bb = b4[l + i * 64];
    ushort4 pk;
    pk.x = bf16_bits((v[i].x - mean) * rstd * gg.x + bb.x);
    pk.y = bf16_bits((v[i].y - mean) * rstd * gg.y + bb.y);
    pk.z = bf16_bits((v[i].z - mean) * rstd * gg.z + bb.z);
    pk.w = bf16_bits((v[i].w - mean) * rstd * gg.w + bb.w);
    *reinterpret_cast<ushort4*>(orow + (l + i * 64) * 4) = pk;
  }
}

// ---------------- layernorm kernel (f32 in -> bf16 out) ----------------
__global__ __launch_bounds__(256) void ln_kernel(
    const float* __restrict__ x, const float* __restrict__ g, const float* __restrict__ b,
    bf16* __restrict__ out, int Mrows)
{
  int row = blockIdx.x * 4 + (threadIdx.x >> 6);
  if (row >= Mrows) return;
  ln_row2(x + (size_t)row * 768, g, b, out + (size_t)row * 768, threadIdx.x & 63);
}

// ---------------- fused: 4-matrix weight transpose + ln1 (+opt b2-gather, +opt rescopy) ----------------
// gmode=1: LN source row = x[b2src(row)] (fused gather). nr>0: extra segment
// copies nr rows rdst[rr] = x[(rr&63)*211] (b2 proj residual = cls rows).
__global__ __launch_bounds__(256) void tln_kernel(
    const float* __restrict__ w0, const float* __restrict__ w1,
    const float* __restrict__ w2, const float* __restrict__ w3,
    bf16* __restrict__ d0, bf16* __restrict__ d1,
    bf16* __restrict__ d2, bf16* __restrict__ d3,
    const float* __restrict__ x, const float* __restrict__ g,
    const float* __restrict__ b, bf16* __restrict__ outh, int Mrows,
    int gmode, float* __restrict__ rdst, int nr)
{
  __shared__ float tile[32][33];
  int id = blockIdx.x;
  if (id >= 6912) {
    const int lnb = (Mrows + 3) / 4;
    int seg = id - 6912;
    if (seg < lnb) {
      int row = seg * 4 + (threadIdx.x >> 6);
      if (row < Mrows) {
        int srow = gmode ? b2src(row) : row;
        ln_row2(x + (size_t)srow * 768, g, b, outh + (size_t)row * 768, threadIdx.x & 63);
      }
    } else {
      int rr = (seg - lnb) * 4 + (threadIdx.x >> 6);
      if (rr < nr) {
        const int l = threadIdx.x & 63;
        const float4* src4 = reinterpret_cast<const float4*>(x + (size_t)(rr & 63) * 211 * 768);
        float4* dst4 = reinterpret_cast<float4*>(rdst + (size_t)rr * 768);
#pragma unroll
        for (int i = 0; i < 3; ++i) dst4[l + i * 64] = src4[l + i * 64];
      }
    }
    return;
  }
  const float* in; bf16* out; int R, C, tt;
  if (id < 1728)      { in = w0; out = d0; R = 768;  C = 2304; tt = id; }
  else if (id < 2304) { in = w1; out = d1; R = 768;  C = 768;  tt = id - 1728; }
  else if (id < 4608) { in = w2; out = d2; R = 768;  C = 3072; tt = id - 2304; }
  else                { in = w3; out = d3; R = 3072; C = 768;  tt = id - 4608; }
  const int tc = C >> 5;
  int c0 = (tt % tc) * 32, r0 = (tt / tc) * 32;
  int tx = threadIdx.x & 31, ty = threadIdx.x >> 5;
#pragma unroll
  for (int i = 0; i < 4; ++i) {
    int rr = ty + i * 8;
    tile[rr][tx] = in[(size_t)(r0 + rr) * C + c0 + tx];
  }
  __syncthreads();
#pragma unroll
  for (int i = 0; i < 4; ++i) {
    int c = ty + i * 8;
    out[(size_t)(c0 + c) * R + r0 + tx] = __float2bfloat16(tile[tx][c]);
  }
}

// ---------------- head layernorm (row 0 of each sequence) -> output (f32) ----------------
__global__ __launch_bounds__(256) void ln_head_kernel(
    const float* __restrict__ x, int tokstride, const float* __restrict__ g,
    const float* __restrict__ b, float* __restrict__ out, int nbb, int mode)
{
  int bb = blockIdx.x * 4 + (threadIdx.x >> 6);
  if (bb >= nbb) return;
  int l = threadIdx.x & 63;
  const float* xr = x + (size_t)bb * tokstride * 768;
  float v[12]; float s = 0.f;
#pragma unroll
  for (int i = 0; i < 12; ++i) { v[i] = xr[l + i * 64]; s += v[i]; }
#pragma unroll
  for (int d = 1; d < 64; d <<= 1) s += __shfl_xor(s, d);
  float mean = s * (1.f / 768.f);
  float s2 = 0.f;
#pragma unroll
  for (int i = 0; i < 12; ++i) { float t = v[i] - mean; s2 += t * t; }
#pragma unroll
  for (int d = 1; d < 64; d <<= 1) s2 += __shfl_xor(s2, d);
  float rstd = rsqrtf(s2 * (1.f / 768.f) + 1e-6f);
  float scale = mode ? 0.25f : 1.f;
  int b_ = mode ? (bb & 63) : bb;
  int off = mode ? (1 + (bb >> 6)) * 768 : 0;
  float* orow = out + (size_t)b_ * 3840 + off;
#pragma unroll
  for (int i = 0; i < 12; ++i) {
    orow[l + i * 64] = ((v[i] - mean) * rstd * g[l + i * 64] + b[l + i * 64]) * scale;
  }
}

// ---------------- fused patch im2col + convw cast (f32 -> bf16) ----------------
__global__ void prep_kernel(const float* __restrict__ x, bf16* __restrict__ pm,
                            const float* __restrict__ convw, bf16* __restrict__ cw)
{
  int idx = blockIdx.x * 256 + threadIdx.x;
  if (idx < 13440 * 768) {
    int k = idx % 768;
    int m = idx / 768;
    int b = m / 210, p = m % 210;
    int py = p / 10, px = p % 10;
    int c = k >> 8, ij = k & 255, i = ij >> 4, j = ij & 15;
    pm[idx] = __float2bfloat16(x[(((size_t)b * 3 + c) * 256 + py * 12 + i) * 128 + px * 12 + j]);
  } else {
    int idx2 = idx - 13440 * 768;
    if (idx2 < 768 * 768) cw[idx2] = __float2bfloat16(convw[idx2]);
  }
}

// ---------------- assemble t = [cls | patches] + pos + SIE*sie[cid] (f32) ----------------
__global__ void assemble_kernel(
    const bf16* __restrict__ y, const float* __restrict__ cls, const float* __restrict__ pos,
    const float* __restrict__ sie, const int* __restrict__ cids, float* __restrict__ tA)
{
  int idx = blockIdx.x * 256 + threadIdx.x;
  if (idx >= 13504 * 768) return;
  int d = idx % 768;
  int t = (idx / 768) % 211;
  int b = idx / (768 * 211);
  float v = pos[t * 768 + d] + 3.0f * sie[cids[b] * 768 + d];
  if (t == 0) v += cls[d];
  else v += __bfloat162float(y[((size_t)b * 210 + (t - 1)) * 768 + d]);
  tA[idx] = v;
}

// ---------------- host orchestration ----------------
struct BlkP {
  const float *ln1_g, *ln1_b, *qkv_w, *qkv_b, *proj_w, *proj_b;
  const float *ln2_g, *ln2_b, *fc1_w, *fc1_b, *fc2_w, *fc2_b;
};

extern "C" void kernel_launch(void* const* d_in, const int* in_sizes, int n_in,
                              void* d_out, int out_size, void* d_ws, size_t ws_size,
                              hipStream_t stream)
{
  (void)in_sizes; (void)n_in; (void)out_size; (void)ws_size;
  const float* xin   = (const float*)d_in[0];
  const int*   cids  = (const int*)  d_in[1];
  const float* convw = (const float*)d_in[2];
  const float* convb = (const float*)d_in[3];
  const float* cls   = (const float*)d_in[4];
  const float* pos   = (const float*)d_in[5];
  const float* sie   = (const float*)d_in[6];
  float* out = (float*)d_out;

  // workspace layout (bytes)
  char* ws = (char*)d_ws;
  bf16*  qkvT = (bf16*)(ws + 0);            // 2304x768 bf16 (also convw_bf slot)
  bf16*  projT = (bf16*)(ws + 3538944);     // 768x768
  bf16*  fc1T = (bf16*)(ws + 4718592);      // 3072x768
  bf16*  fc2T = (bf16*)(ws + 9437184);      // 768x3072
  float* tA   = (float*)(ws + 14155776);    // 13504x768 f32
  float* rcb  = (float*)(ws + 55640064);    // b2 residual rows (256x768 f32)
  bf16*  hb   = (bf16*)(ws + 97320960);     // 13568x768 bf16
  // big region [118161408, 201523200): QKV head-blocked buffers / fc1-mid
  bf16*  qb   = (bf16*)(ws + 118161408);    // Q [bbh][pad][64]
  bf16*  kb   = (bf16*)(ws + 143327232);    // K
  bf16*  vb   = (bf16*)(ws + 168493056);    // V compact
  bf16*  big  = (bf16*)(ws + 118161408);    // fc1-mid reuses whole region
  char*  sbuf = ws + 193658880;             // compact head buffers
  float* y0   = (float*)(sbuf);             // 256x768 f32
  bf16*  hb0  = (bf16*)(sbuf + 786432);     // 256x768 bf16
  bf16*  big0 = (bf16*)(sbuf + 1179648);    // 256x3072 bf16
  float* f0b  = (float*)(sbuf + 2752512);   // 256x768 f32
  bf16*  ao   = (bf16*)(ws + 201523200);    // 13568x768 bf16
  bf16*  vTb  = (bf16*)(ws + 222363648);    // V^T buffer (head path only)

  dim3 blk(256);

  // full pre-norm ViT block applied in-place on xbuf (the 11 stacked blocks)
  auto apply_block = [&](float* xbuf, const BlkP& p, int nb, int ntok_) {
    const int M = nb * ntok_;
    const int gm = (M + 127) / 128;
    const int pad = (ntok_ == NTOK) ? 224 : 64;
    tln_kernel<<<dim3(6912 + (M + 3) / 4), blk, 0, stream>>>(
        p.qkv_w, p.proj_w, p.fc1_w, p.fc2_w, qkvT, projT, fc1T, fc2T,
        xbuf, p.ln1_g, p.ln1_b, hb, M, 0, nullptr, 0);
    gemm_db<false, false, bf16, 2><<<dim3(gm * 18), blk, 0, stream>>>(
        hb, qkvT, p.qkv_b, nullptr, (bf16*)nullptr, M, 2304, 768, 18, 768, 0, 0,
        qb, kb, vb, pad, ntok_, 0);
    attn_kernel<14, false><<<dim3(nb, NHEAD), blk, 0, stream>>>(qb, kb, vb, ao, ntok_, pad);
    gemm_db<false, true, float, 0><<<dim3(gm * 6), blk, 0, stream>>>(
        ao, projT, p.proj_b, xbuf, xbuf, M, 768, 768, 6, 768, 768, 768,
        nullptr, nullptr, nullptr, 0, 1, 0);
    ln_kernel<<<dim3((M + 3) / 4), blk, 0, stream>>>(xbuf, p.ln2_g, p.ln2_b, hb, M);
    gemm_db<true, false, bf16, 0><<<dim3(gm * 24), blk, 0, stream>>>(
        hb, fc1T, p.fc1_b, nullptr, big, M, 3072, 768, 24, 768, 3072, 3072,
        nullptr, nullptr, nullptr, 0, 1, 0);
    gemm_db<false, true, float, 0><<<dim3(gm * 6), blk, 0, stream>>>(
        big, fc2T, p.fc2_b, xbuf, xbuf, M, 768, 3072, 6, 3072, 768, 768,
        nullptr, nullptr, nullptr, 0, 1, 0);
  };

  // head block: only token 0 consumed downstream. gmode=1 fuses the b2 gather
  // into the LN read; resp/rstride select the proj residual source.
  auto apply_head_block = [&](const float* xsrc, const BlkP& p, int nb, int ntok_,
                              const float* ng, const float* nbias, int mode,
                              int gmode, const float* resp, int rstride) {
    const int M = nb * ntok_;
    const int gm = (M + 127) / 128;
    const int gm0 = (nb + 127) / 128;
    const int pad = (ntok_ == NTOK) ? 224 : 64;
    const int nr = gmode ? nb : 0;
    tln_kernel<<<dim3(6912 + (M + 3) / 4 + (nr + 3) / 4), blk, 0, stream>>>(
        p.qkv_w, p.proj_w, p.fc1_w, p.fc2_w, qkvT, projT, fc1T, fc2T,
        xsrc, p.ln1_g, p.ln1_b, hb, M, gmode, rcb, nr);
    // KV for all tokens (cols 768..2303 -> coff=768)
    gemm_db<false, false, bf16, 2><<<dim3(gm * 12), blk, 0, stream>>>(
        hb, qkvT + 768 * 768, p.qkv_b + 768, nullptr, (bf16*)nullptr,
        M, 1536, 768, 12, 768, 0, 0, qb, kb, vb, pad, ntok_, 768);
    // Q for token-0 rows only (compact M = nb, strided A; ntd=1 -> bb=row, tok=0)
    gemm_db<false, false, bf16, 2><<<dim3(gm0 * 6), blk, 0, stream>>>(
        hb, qkvT, p.qkv_b, nullptr, (bf16*)nullptr,
        nb, 768, 768, 6, ntok_ * 768, 0, 0, qb, kb, vb, pad, 1, 0);
    vtrans_kernel<<<dim3(nb, NHEAD), blk, 0, stream>>>(vb, vTb, ntok_, pad);
    if (ntok_ == NTOK)
      attn_kernel<14, true><<<dim3(nb, NHEAD), blk, 0, stream>>>(qb, kb, vTb, ao, ntok_, pad);
    else
      attn_kernel<4, true><<<dim3(nb, NHEAD), blk, 0, stream>>>(qb, kb, vTb, ao, ntok_, pad);
    gemm_db<false, true, float, 0><<<dim3(gm0 * 6), blk, 0, stream>>>(
        ao, projT, p.proj_b, resp, y0, nb, 768, 768, 6, ntok_ * 768, rstride, 768,
        nullptr, nullptr, nullptr, 0, 1, 0);
    ln_kernel<<<dim3((nb + 3) / 4), blk, 0, stream>>>(y0, p.ln2_g, p.ln2_b, hb0, nb);
    gemm_db<true, false, bf16, 0><<<dim3(gm0 * 24), blk, 0, stream>>>(
        hb0, fc1T, p.fc1_b, nullptr, big0, nb, 3072, 768, 24, 768, 3072, 3072,
        nullptr, nullptr, nullptr, 0, 1, 0);
    gemm_db<false, true, float, 0><<<dim3(gm0 * 6), blk, 0, stream>>>(
        big0, fc2T, p.fc2_b, y0, f0b, nb, 768, 3072, 6, 3072, 768, 768,
        nullptr, nullptr, nullptr, 0, 1, 0);
    ln_head_kernel<<<dim3((nb + 3) / 4), blk, 0, stream>>>(
        f0b, 1, ng, nbias, out, nb, mode);
  };

  // 1) patch embed: im2col+cast -> GEMM(conv) -> assemble
  {
    int total = 13440 * 768 + 768 * 768;
    prep_kernel<<<dim3((total + 255) / 256), blk, 0, stream>>>(xin, big, convw, qkvT);
    gemm_db<false, false, bf16, 0><<<dim3(105 * 6), blk, 0, stream>>>(
        big, qkvT, convb, nullptr, ao, 13440, 768, 768, 6, 768, 768, 768,
        nullptr, nullptr, nullptr, 0, 1, 0);
    total = 13504 * 768;
    assemble_kernel<<<dim3((total + 255) / 256), blk, 0, stream>>>(ao, cls, pos, sie, cids, tA);
  }

  // 2) 11 stacked blocks (lead-dim DEPTH params)
  const float* bp[12];
  for (int i = 0; i < 12; ++i) bp[i] = (const float*)d_in[7 + i];
  for (int dd = 0; dd < DEPTH; ++dd) {
    BlkP p;
    p.ln1_g = bp[0] + dd * 768;                p.ln1_b = bp[1] + dd * 768;
    p.qkv_w = bp[2] + (size_t)dd * 768 * 2304; p.qkv_b = bp[3] + dd * 2304;
    p.proj_w = bp[4] + (size_t)dd * 768 * 768; p.proj_b = bp[5] + dd * 768;
    p.ln2_g = bp[6] + dd * 768;                p.ln2_b = bp[7] + dd * 768;
    p.fc1_w = bp[8] + (size_t)dd * 768 * 3072; p.fc1_b = bp[9] + dd * 3072;
    p.fc2_w = bp[10] + (size_t)dd * 3072 * 768; p.fc2_b = bp[11] + dd * 768;
    apply_block(tA, p, 64, NTOK);
  }

  // 3) b1 branch: f0 = LN(block(t))[:,0]  (token-0 head path; res = tA strided)
  {
    BlkP p;
    p.ln1_g = (const float*)d_in[19]; p.ln1_b = (const float*)d_in[20];
    p.qkv_w = (const float*)d_in[21]; p.qkv_b = (const float*)d_in[22];
    p.proj_w = (const float*)d_in[23]; p.proj_b = (const float*)d_in[24];
    p.ln2_g = (const float*)d_in[25]; p.ln2_b = (const float*)d_in[26];
    p.fc1_w = (const float*)d_in[27]; p.fc1_b = (const float*)d_in[28];
    p.fc2_w = (const float*)d_in[29]; p.fc2_b = (const float*)d_in[30];
    apply_head_block(tA, p, 64, NTOK,
                     (const float*)d_in[31], (const float*)d_in[32], 0,
                     0, tA, NTOK * 768);
  }

  // 4) b2 branch: gather fused into tln (gmode=1); res = rcb (cls rows copy)
  {
    BlkP p;
    p.ln1_g = (const float*)d_in[33]; p.ln1_b = (const float*)d_in[34];
    p.qkv_w = (const float*)d_in[35]; p.qkv_b = (const float*)d_in[36];
    p.proj_w = (const float*)d_in[37]; p.proj_b = (const float*)d_in[38];
    p.ln2_g = (const float*)d_in[39]; p.ln2_b = (const float*)d_in[40];
    p.fc1_w = (const float*)d_in[41]; p.fc1_b = (const float*)d_in[42];
    p.fc2_w = (const float*)d_in[43]; p.fc2_b = (const float*)d_in[44];
    apply_head_block(tA, p, 256, 53,
                     (const float*)d_in[45], (const float*)d_in[46], 1,
                     1, rcb, 768);
  }
}

// Round 17
// 4865.181 us; speedup vs baseline: 1.0557x; 1.0557x over previous
//
#include <hip/hip_runtime.h>
#include <hip/hip_bf16.h>
#include <cstdint>
#include <cstddef>
#include <math.h>

using bf16 = __hip_bfloat16;
typedef __bf16 bf16x8 __attribute__((ext_vector_type(8)));
typedef float f32x4 __attribute__((ext_vector_type(4)));

// ---------------- constants ----------------
static constexpr int NHEAD = 12;
static constexpr int NTOK  = 211;   // 210 patches + cls
static constexpr int DEPTH = 11;

// ---------------- global->LDS direct load ----------------
static __device__ __forceinline__ void gload_lds16(const bf16* g, bf16* lds) {
  __builtin_amdgcn_global_load_lds(
      (const __attribute__((address_space(1))) uint32_t*)g,
      (__attribute__((address_space(3))) uint32_t*)lds,
      16, 0, 0);
}

__device__ __forceinline__ float gelu_f(float x) {
  float u = x * (0.7978845608f + 0.0356774081f * x * x);
  float t = 1.f - 2.f / (__expf(2.f * u) + 1.f);
  return 0.5f * x * (1.f + t);
}

static __device__ __forceinline__ unsigned short bf16_bits(float x) {
  return __builtin_bit_cast(unsigned short, __float2bfloat16(x));
}

// b2 shuffle: gathered row -> source row index within its batch's tA sequence
static __device__ __forceinline__ int b2src(int row) {
  int bb = row / 53, jj = row - bb * 53;
  int i = bb >> 6, b = bb & 63;
  int src;
  if (jj == 0) src = 0;
  else {
    int jx = i * 52 + (jj - 1);
    int mm = (jx & 1) * 105 + (jx >> 1);
    src = (mm < 206) ? (5 + mm) : (1 + (mm - 206));
  }
  return b * 211 + src;
}

// ---------------- m97-style double-buffered TN GEMM, 128x128 tile, 16x16x32 MFMA ----------------
// (round-9/13/15 verified: 111us fc1-class, bank conflicts 0.)
// OUT=0: C[r*sC+col] = A@Bt + bias (+gelu, +res[r*sR+col]); CT f32 or bf16.
//   f32 path: direct per-element stores (16 consecutive lanes coalesce into
//   64B segments; round-16's LDS-bounce "vectorization" regressed -20%).
// OUT=2: qkv-split epilogue -> head-blocked Q/K/V [(bb*12+h)][pad][64].
template <bool GELU, bool RES, typename CT, int OUT>
__global__ __launch_bounds__(256) void gemm_db(
    const bf16* __restrict__ A, const bf16* __restrict__ Bt,
    const float* __restrict__ bias, const float* __restrict__ res,
    CT* __restrict__ C, int M, int N, int K, int gn, int sA, int sR, int sC,
    bf16* __restrict__ qh, bf16* __restrict__ kh, bf16* __restrict__ vh,
    int pad, int ntd, int coff)
{
  __shared__ bf16 sb[2][8192];   // 32 KB total

  const int tid = threadIdx.x;
  const int w = tid >> 6, l = tid & 63;
  const int lr = l & 15, lg = l >> 4;
  const int wr = (w >> 1) * 64, wc = (w & 1) * 64;

  const int nwg = gridDim.x, lin = blockIdx.x;
  const int q = nwg >> 3, r = nwg & 7;
  const int xcd = lin & 7, pos = lin >> 3;
  const int wg = (xcd < r ? xcd * (q + 1) : r * (q + 1) + (xcd - r) * q) + pos;
  const int bm0 = (wg / gn) * 128, bn0 = (wg % gn) * 128;

  f32x4 acc[4][4];
#pragma unroll
  for (int i = 0; i < 4; ++i)
#pragma unroll
    for (int j = 0; j < 4; ++j) acc[i][j] = f32x4{0.f, 0.f, 0.f, 0.f};

  size_t aof[2], bof[2]; int dst[2];
#pragma unroll
  for (int j = 0; j < 2; ++j) {
    const int c = j * 256 + tid;
    const int row = c >> 2;
    const int ch = (c & 3) ^ ((row >> 1) & 3);
    int ar = bm0 + row; if (ar >= M) ar = M - 1;
    aof[j] = (size_t)ar * sA + ch * 8;
    bof[j] = (size_t)(bn0 + row) * K + ch * 8;
    dst[j] = c * 8;
  }

  const int nt = K >> 5;

  auto stage = [&](int t) {
    bf16* s = sb[t & 1];
    const size_t ko = (size_t)t * 32;
    gload_lds16(A + aof[0] + ko, s + dst[0]);
    gload_lds16(A + aof[1] + ko, s + dst[1]);
    gload_lds16(Bt + bof[0] + ko, s + 4096 + dst[0]);
    gload_lds16(Bt + bof[1] + ko, s + 4096 + dst[1]);
  };

  stage(0);
  __syncthreads();

  const int swz = (lg ^ ((lr >> 1) & 3)) * 8;

  for (int t = 0; t < nt; ++t) {
    if (t + 1 < nt) stage(t + 1);
    const bf16* As = sb[t & 1];
    const bf16* Bs = As + 4096;
    bf16x8 af[4], bv[4];
#pragma unroll
    for (int mi = 0; mi < 4; ++mi)
      af[mi] = *(const bf16x8*)(As + (wr + mi * 16 + lr) * 32 + swz);
#pragma unroll
    for (int ni = 0; ni < 4; ++ni)
      bv[ni] = *(const bf16x8*)(Bs + (wc + ni * 16 + lr) * 32 + swz);
#pragma unroll
    for (int mi = 0; mi < 4; ++mi)
#pragma unroll
      for (int ni = 0; ni < 4; ++ni)
        acc[mi][ni] = __builtin_amdgcn_mfma_f32_16x16x32_bf16(af[mi], bv[ni], acc[mi][ni], 0, 0, 0);
    __syncthreads();
  }

  if constexpr (OUT == 2 || sizeof(CT) == 2) {
    // ---- bf16/qkv out: LDS-bounce (bank-spread XOR), then 16B vector stores ----
    char* lb = (char*)sb;     // 32 KB = 128 rows x 256 B
#pragma unroll
    for (int mi = 0; mi < 4; ++mi) {
#pragma unroll
      for (int ni = 0; ni < 4; ++ni) {
        const int cloc = wc + ni * 16 + lr;
        const float bvl = bias[bn0 + cloc];
#pragma unroll
        for (int r2 = 0; r2 < 4; ++r2) {
          const int rowl = wr + mi * 16 + lg * 4 + r2;
          float v = acc[mi][ni][r2] + bvl;
          if constexpr (GELU) v = gelu_f(v);
          *(unsigned short*)(lb + rowl * 256 + ((cloc * 2) ^ (((rowl >> 1) & 6) << 4))) =
              bf16_bits(v);
        }
      }
    }
    __syncthreads();
#pragma unroll
    for (int j = 0; j < 8; ++j) {
      const int flat = j * 256 + tid;
      const int row = flat >> 4, ch = flat & 15;
      const int grow = bm0 + row;
      if (grow < M) {
        const f32x4 v = *(const f32x4*)(lb + row * 256 + ((ch * 16) ^ (((row >> 1) & 6) << 4)));
        if constexpr (OUT == 2) {
          const int col0 = bn0 + ch * 8 + coff;
          const int region = (col0 >= 1536) ? 2 : (col0 >= 768 ? 1 : 0);
          const int c7 = col0 - region * 768;
          const int h = c7 >> 6, d = c7 & 63;
          const int bb2 = grow / ntd;
          const int tok = grow - bb2 * ntd;
          bf16* db = (region == 0) ? qh : ((region == 1) ? kh : vh);
          *(f32x4*)((char*)db + (((size_t)(bb2 * 12 + h) * pad + tok) * 64 + d) * 2) = v;
        } else {
          *(f32x4*)((char*)C + ((size_t)grow * sC + bn0 + ch * 8) * 2) = v;
        }
      }
    }
  } else {
    // ---- f32 out: direct stores (coalesce across 16-lane col groups) ----
#pragma unroll
    for (int mi = 0; mi < 4; ++mi) {
#pragma unroll
      for (int ni = 0; ni < 4; ++ni) {
        const int col = bn0 + wc + ni * 16 + lr;
        const float bvl = bias[col];
#pragma unroll
        for (int r2 = 0; r2 < 4; ++r2) {
          const int row = bm0 + wr + mi * 16 + lg * 4 + r2;
          if (row < M) {
            float v = acc[mi][ni][r2] + bvl;
            if constexpr (GELU) v = gelu_f(v);
            if constexpr (RES) v += res[(size_t)row * sR + col];
            C[(size_t)row * sC + col] = v;
          }
        }
      }
    }
  }
}

// ---------------- V transpose (head path only): vcomp[bbh][tok][64] -> vT[bbh][d][pad] ----------------
__global__ __launch_bounds__(256) void vtrans_kernel(
    const bf16* __restrict__ vcomp, bf16* __restrict__ vT, int ntok, int pad)
{
  __shared__ unsigned short t[224 * 65];
  const int bb = blockIdx.x, h = blockIdx.y;
  const unsigned short* src = (const unsigned short*)vcomp + (size_t)(bb * 12 + h) * pad * 64;
  for (int idx = threadIdx.x; idx < ntok * 64; idx += 256) {
    int tok = idx >> 6, d = idx & 63;
    t[tok * 65 + d] = src[idx];
  }
  __syncthreads();
  unsigned short* dstp = (unsigned short*)vT + (size_t)(bb * 12 + h) * 64 * pad;
  for (int idx = threadIdx.x; idx < 64 * ntok; idx += 256) {
    int d = idx / ntok, tok = idx - d * ntok;
    dstp[(size_t)d * pad + tok] = t[tok * 65 + d];
  }
}

// ---------------- fused attention: one block per (bb, head); head-blocked Q/K ----------------
template <int NKF, bool ONLY0>
__global__ __launch_bounds__(256) void attn_kernel(
    const bf16* __restrict__ qb, const bf16* __restrict__ kb,
    const bf16* __restrict__ vsrc, bf16* __restrict__ ao, int ntok, int pad)
{
  constexpr int NPAD = NKF * 16;
  constexpr int VST = NPAD + 8;       // Vt row stride (elems); 16B aligned
  __shared__ bf16 Pl[4][16][NPAD];
  __shared__ __bf16 Vt[ONLY0 ? 1 : 64][ONLY0 ? 1 : VST];
  const int bb = blockIdx.x;
  const int h = blockIdx.y;
  const int tid = threadIdx.x;
  const int w = tid >> 6, l = tid & 63;
  const int lr = l & 15, lg = l >> 4;
  const int bbh = bb * 12 + h;
  const __bf16* qbase = reinterpret_cast<const __bf16*>(qb) + (size_t)bbh * pad * 64;
  const __bf16* kbase = reinterpret_cast<const __bf16*>(kb) + (size_t)bbh * pad * 64;
  const __bf16* vglob = reinterpret_cast<const __bf16*>(vsrc) +
                        (ONLY0 ? (size_t)bbh * 64 * pad : (size_t)bbh * pad * 64);

  if constexpr (!ONLY0) {
    for (int idx = tid; idx < ntok * 64; idx += 256) {
      const int tok = idx >> 6, d = idx & 63;
      Vt[d][tok] = vglob[idx];
    }
    __syncthreads();
  }
  if (ONLY0 && w > 0) return;   // 1-wave head path; no barrier below

  for (int qt = w; qt < (ONLY0 ? 1 : NKF); qt += 4) {
    int qrow = qt * 16 + lr; if (qrow >= ntok) qrow = ntok - 1;
    const __bf16* qp = qbase + qrow * 64 + lg * 8;
    const bf16x8 qf0 = *reinterpret_cast<const bf16x8*>(qp);
    const bf16x8 qf1 = *reinterpret_cast<const bf16x8*>(qp + 32);

    f32x4 s[NKF];
#pragma unroll
    for (int kf = 0; kf < NKF; ++kf) {
      int krow = kf * 16 + lr; if (krow >= ntok) krow = ntok - 1;
      const __bf16* kp = kbase + krow * 64 + lg * 8;
      f32x4 a = f32x4{0.f, 0.f, 0.f, 0.f};
      a = __builtin_amdgcn_mfma_f32_16x16x32_bf16(qf0, *reinterpret_cast<const bf16x8*>(kp), a, 0, 0, 0);
      a = __builtin_amdgcn_mfma_f32_16x16x32_bf16(qf1, *reinterpret_cast<const bf16x8*>(kp + 32), a, 0, 0, 0);
      s[kf] = a;
    }

    float rs[4];
#pragma unroll
    for (int r = 0; r < 4; ++r) {
      float mx = -1e30f;
#pragma unroll
      for (int kf = 0; kf < NKF; ++kf)
        if (kf * 16 + lr < ntok) mx = fmaxf(mx, s[kf][r]);
#pragma unroll
      for (int d = 1; d < 16; d <<= 1) mx = fmaxf(mx, __shfl_xor(mx, d));
      float sum = 0.f;
#pragma unroll
      for (int kf = 0; kf < NKF; ++kf) {
        float p = 0.f;
        if (kf * 16 + lr < ntok) p = __expf((s[kf][r] - mx) * 0.125f);
        sum += p;
        Pl[w][lg * 4 + r][kf * 16 + lr] = __float2bfloat16(p);
      }
#pragma unroll
      for (int d = 1; d < 16; d <<= 1) sum += __shfl_xor(sum, d);
      rs[r] = sum;
    }
    __builtin_amdgcn_s_waitcnt(0);  // lgkm: Pl writes visible to this wave

    f32x4 o[4];
#pragma unroll
    for (int ni = 0; ni < 4; ++ni) o[ni] = f32x4{0.f, 0.f, 0.f, 0.f};
#pragma unroll
    for (int ks = 0; ks < NPAD / 32; ++ks) {
      const bf16x8 pa = *reinterpret_cast<const bf16x8*>(&Pl[w][lr][ks * 32 + lg * 8]);
#pragma unroll
      for (int ni = 0; ni < 4; ++ni) {
        bf16x8 vb;
        if constexpr (ONLY0) {
          vb = *reinterpret_cast<const bf16x8*>(
              vglob + (size_t)(ni * 16 + lr) * pad + ks * 32 + lg * 8);
        } else {
          vb = *reinterpret_cast<const bf16x8*>(&Vt[ni * 16 + lr][ks * 32 + lg * 8]);
        }
        o[ni] = __builtin_amdgcn_mfma_f32_16x16x32_bf16(pa, vb, o[ni], 0, 0, 0);
      }
    }
#pragma unroll
    for (int ni = 0; ni < 4; ++ni)
#pragma unroll
      for (int r = 0; r < 4; ++r) {
        int qq = qt * 16 + lg * 4 + r;
        if (qq < (ONLY0 ? 1 : ntok)) {
          float val = o[ni][r] / rs[r];
          ao[((size_t)bb * ntok + qq) * 768 + h * 64 + ni * 16 + lr] = __float2bfloat16(val);
        }
      }
  }
}

// ---------------- layernorm body (device), explicit source row pointer ----------------
static __device__ __forceinline__ void ln_row2(
    const float* __restrict__ xrow, const float* __restrict__ g, const float* __restrict__ b,
    bf16* __restrict__ outrow, int l)
{
  const float4* xr = reinterpret_cast<const float4*>(xrow);
  float4 v[3]; float s = 0.f;
#pragma unroll
  for (int i = 0; i < 3; ++i) {
    v[i] = xr[l + i * 64];
    s += v[i].x + v[i].y + v[i].z + v[i].w;
  }
#pragma unroll
  for (int d = 1; d < 64; d <<= 1) s += __shfl_xor(s, d);
  float mean = s * (1.f / 768.f);
  float s2 = 0.f;
#pragma unroll
  for (int i = 0; i < 3; ++i) {
    float a0 = v[i].x - mean, a1 = v[i].y - mean, a2 = v[i].z - mean, a3 = v[i].w - mean;
    s2 += a0 * a0 + a1 * a1 + a2 * a2 + a3 * a3;
  }
#pragma unroll
  for (int d = 1; d < 64; d <<= 1) s2 += __shfl_xor(s2, d);
  float rstd = rsqrtf(s2 * (1.f / 768.f) + 1e-6f);
  const float4* g4 = reinterpret_cast<const float4*>(g);
  const float4* b4 = reinterpret_cast<const float4*>(b);
  unsigned short* orow = reinterpret_cast<unsigned short*>(outrow);
#pragma unroll
  for (int i = 0; i < 3; ++i) {
    float4 gg = g4[l + i * 64], bb = b4[l + i * 64];
    ushort4 pk;
    pk.x = bf16_bits((v[i].x - mean) * rstd * gg.x + bb.x);
    pk.y = bf16_bits((v[i].y - mean) * rstd * gg.y + bb.y);
    pk.z = bf16_bits((v[i].z - mean) * rstd * gg.z + bb.z);
    pk.w = bf16_bits((v[i].w - mean) * rstd * gg.w + bb.w);
    *reinterpret_cast<ushort4*>(orow + (l + i * 64) * 4) = pk;
  }
}

// ---------------- layernorm kernel (f32 in -> bf16 out) ----------------
__global__ __launch_bounds__(256) void ln_kernel(
    const float* __restrict__ x, const float* __restrict__ g, const float* __restrict__ b,
    bf16* __restrict__ out, int Mrows)
{
  int row = blockIdx.x * 4 + (threadIdx.x >> 6);
  if (row >= Mrows) return;
  ln_row2(x + (size_t)row * 768, g, b, out + (size_t)row * 768, threadIdx.x & 63);
}

// ---------------- fused: 4-matrix weight transpose + ln1 (+opt b2-gather, +opt rescopy) ----------------
__global__ __launch_bounds__(256) void tln_kernel(
    const float* __restrict__ w0, const float* __restrict__ w1,
    const float* __restrict__ w2, const float* __restrict__ w3,
    bf16* __restrict__ d0, bf16* __restrict__ d1,
    bf16* __restrict__ d2, bf16* __restrict__ d3,
    const float* __restrict__ x, const float* __restrict__ g,
    const float* __restrict__ b, bf16* __restrict__ outh, int Mrows,
    int gmode, float* __restrict__ rdst, int nr)
{
  __shared__ float tile[32][33];
  int id = blockIdx.x;
  if (id >= 6912) {
    const int lnb = (Mrows + 3) / 4;
    int seg = id - 6912;
    if (seg < lnb) {
      int row = seg * 4 + (threadIdx.x >> 6);
      if (row < Mrows) {
        int srow = gmode ? b2src(row) : row;
        ln_row2(x + (size_t)srow * 768, g, b, outh + (size_t)row * 768, threadIdx.x & 63);
      }
    } else {
      int rr = (seg - lnb) * 4 + (threadIdx.x >> 6);
      if (rr < nr) {
        const int l = threadIdx.x & 63;
        const float4* src4 = reinterpret_cast<const float4*>(x + (size_t)(rr & 63) * 211 * 768);
        float4* dst4 = reinterpret_cast<float4*>(rdst + (size_t)rr * 768);
#pragma unroll
        for (int i = 0; i < 3; ++i) dst4[l + i * 64] = src4[l + i * 64];
      }
    }
    return;
  }
  const float* in; bf16* out; int R, C, tt;
  if (id < 1728)      { in = w0; out = d0; R = 768;  C = 2304; tt = id; }
  else if (id < 2304) { in = w1; out = d1; R = 768;  C = 768;  tt = id - 1728; }
  else if (id < 4608) { in = w2; out = d2; R = 768;  C = 3072; tt = id - 2304; }
  else                { in = w3; out = d3; R = 3072; C = 768;  tt = id - 4608; }
  const int tc = C >> 5;
  int c0 = (tt % tc) * 32, r0 = (tt / tc) * 32;
  int tx = threadIdx.x & 31, ty = threadIdx.x >> 5;
#pragma unroll
  for (int i = 0; i < 4; ++i) {
    int rr = ty + i * 8;
    tile[rr][tx] = in[(size_t)(r0 + rr) * C + c0 + tx];
  }
  __syncthreads();
#pragma unroll
  for (int i = 0; i < 4; ++i) {
    int c = ty + i * 8;
    out[(size_t)(c0 + c) * R + r0 + tx] = __float2bfloat16(tile[tx][c]);
  }
}

// ---------------- head layernorm (row 0 of each sequence) -> output (f32) ----------------
__global__ __launch_bounds__(256) void ln_head_kernel(
    const float* __restrict__ x, int tokstride, const float* __restrict__ g,
    const float* __restrict__ b, float* __restrict__ out, int nbb, int mode)
{
  int bb = blockIdx.x * 4 + (threadIdx.x >> 6);
  if (bb >= nbb) return;
  int l = threadIdx.x & 63;
  const float* xr = x + (size_t)bb * tokstride * 768;
  float v[12]; float s = 0.f;
#pragma unroll
  for (int i = 0; i < 12; ++i) { v[i] = xr[l + i * 64]; s += v[i]; }
#pragma unroll
  for (int d = 1; d < 64; d <<= 1) s += __shfl_xor(s, d);
  float mean = s * (1.f / 768.f);
  float s2 = 0.f;
#pragma unroll
  for (int i = 0; i < 12; ++i) { float t = v[i] - mean; s2 += t * t; }
#pragma unroll
  for (int d = 1; d < 64; d <<= 1) s2 += __shfl_xor(s2, d);
  float rstd = rsqrtf(s2 * (1.f / 768.f) + 1e-6f);
  float scale = mode ? 0.25f : 1.f;
  int b_ = mode ? (bb & 63) : bb;
  int off = mode ? (1 + (bb >> 6)) * 768 : 0;
  float* orow = out + (size_t)b_ * 3840 + off;
#pragma unroll
  for (int i = 0; i < 12; ++i) {
    orow[l + i * 64] = ((v[i] - mean) * rstd * g[l + i * 64] + b[l + i * 64]) * scale;
  }
}

// ---------------- fused patch im2col + convw cast (f32 -> bf16) ----------------
__global__ void prep_kernel(const float* __restrict__ x, bf16* __restrict__ pm,
                            const float* __restrict__ convw, bf16* __restrict__ cw)
{
  int idx = blockIdx.x * 256 + threadIdx.x;
  if (idx < 13440 * 768) {
    int k = idx % 768;
    int m = idx / 768;
    int b = m / 210, p = m % 210;
    int py = p / 10, px = p % 10;
    int c = k >> 8, ij = k & 255, i = ij >> 4, j = ij & 15;
    pm[idx] = __float2bfloat16(x[(((size_t)b * 3 + c) * 256 + py * 12 + i) * 128 + px * 12 + j]);
  } else {
    int idx2 = idx - 13440 * 768;
    if (idx2 < 768 * 768) cw[idx2] = __float2bfloat16(convw[idx2]);
  }
}

// ---------------- assemble t = [cls | patches] + pos + SIE*sie[cid] (f32) ----------------
__global__ void assemble_kernel(
    const bf16* __restrict__ y, const float* __restrict__ cls, const float* __restrict__ pos,
    const float* __restrict__ sie, const int* __restrict__ cids, float* __restrict__ tA)
{
  int idx = blockIdx.x * 256 + threadIdx.x;
  if (idx >= 13504 * 768) return;
  int d = idx % 768;
  int t = (idx / 768) % 211;
  int b = idx / (768 * 211);
  float v = pos[t * 768 + d] + 3.0f * sie[cids[b] * 768 + d];
  if (t == 0) v += cls[d];
  else v += __bfloat162float(y[((size_t)b * 210 + (t - 1)) * 768 + d]);
  tA[idx] = v;
}

// ---------------- host orchestration ----------------
struct BlkP {
  const float *ln1_g, *ln1_b, *qkv_w, *qkv_b, *proj_w, *proj_b;
  const float *ln2_g, *ln2_b, *fc1_w, *fc1_b, *fc2_w, *fc2_b;
};

extern "C" void kernel_launch(void* const* d_in, const int* in_sizes, int n_in,
                              void* d_out, int out_size, void* d_ws, size_t ws_size,
                              hipStream_t stream)
{
  (void)in_sizes; (void)n_in; (void)out_size; (void)ws_size;
  const float* xin   = (const float*)d_in[0];
  const int*   cids  = (const int*)  d_in[1];
  const float* convw = (const float*)d_in[2];
  const float* convb = (const float*)d_in[3];
  const float* cls   = (const float*)d_in[4];
  const float* pos   = (const float*)d_in[5];
  const float* sie   = (const float*)d_in[6];
  float* out = (float*)d_out;

  // workspace layout (bytes)
  char* ws = (char*)d_ws;
  bf16*  qkvT = (bf16*)(ws + 0);            // 2304x768 bf16 (also convw_bf slot)
  bf16*  projT = (bf16*)(ws + 3538944);     // 768x768
  bf16*  fc1T = (bf16*)(ws + 4718592);      // 3072x768
  bf16*  fc2T = (bf16*)(ws + 9437184);      // 768x3072
  float* tA   = (float*)(ws + 14155776);    // 13504x768 f32
  float* rcb  = (float*)(ws + 55640064);    // b2 residual rows (256x768 f32)
  bf16*  hb   = (bf16*)(ws + 97320960);     // 13568x768 bf16
  // big region [118161408, 201523200): QKV head-blocked buffers / fc1-mid
  bf16*  qb   = (bf16*)(ws + 118161408);    // Q [bbh][pad][64]
  bf16*  kb   = (bf16*)(ws + 143327232);    // K
  bf16*  vb   = (bf16*)(ws + 168493056);    // V compact
  bf16*  big  = (bf16*)(ws + 118161408);    // fc1-mid reuses whole region
  char*  sbuf = ws + 193658880;             // compact head buffers
  float* y0   = (float*)(sbuf);             // 256x768 f32
  bf16*  hb0  = (bf16*)(sbuf + 786432);     // 256x768 bf16
  bf16*  big0 = (bf16*)(sbuf + 1179648);    // 256x3072 bf16
  float* f0b  = (float*)(sbuf + 2752512);   // 256x768 f32
  bf16*  ao   = (bf16*)(ws + 201523200);    // 13568x768 bf16
  bf16*  vTb  = (bf16*)(ws + 222363648);    // V^T buffer (head path only)

  dim3 blk(256);

  // full pre-norm ViT block applied in-place on xbuf (the 11 stacked blocks)
  auto apply_block = [&](float* xbuf, const BlkP& p, int nb, int ntok_) {
    const int M = nb * ntok_;
    const int gm = (M + 127) / 128;
    const int pad = (ntok_ == NTOK) ? 224 : 64;
    tln_kernel<<<dim3(6912 + (M + 3) / 4), blk, 0, stream>>>(
        p.qkv_w, p.proj_w, p.fc1_w, p.fc2_w, qkvT, projT, fc1T, fc2T,
        xbuf, p.ln1_g, p.ln1_b, hb, M, 0, nullptr, 0);
    gemm_db<false, false, bf16, 2><<<dim3(gm * 18), blk, 0, stream>>>(
        hb, qkvT, p.qkv_b, nullptr, (bf16*)nullptr, M, 2304, 768, 18, 768, 0, 0,
        qb, kb, vb, pad, ntok_, 0);
    attn_kernel<14, false><<<dim3(nb, NHEAD), blk, 0, stream>>>(qb, kb, vb, ao, ntok_, pad);
    gemm_db<false, true, float, 0><<<dim3(gm * 6), blk, 0, stream>>>(
        ao, projT, p.proj_b, xbuf, xbuf, M, 768, 768, 6, 768, 768, 768,
        nullptr, nullptr, nullptr, 0, 1, 0);
    ln_kernel<<<dim3((M + 3) / 4), blk, 0, stream>>>(xbuf, p.ln2_g, p.ln2_b, hb, M);
    gemm_db<true, false, bf16, 0><<<dim3(gm * 24), blk, 0, stream>>>(
        hb, fc1T, p.fc1_b, nullptr, big, M, 3072, 768, 24, 768, 3072, 3072,
        nullptr, nullptr, nullptr, 0, 1, 0);
    gemm_db<false, true, float, 0><<<dim3(gm * 6), blk, 0, stream>>>(
        big, fc2T, p.fc2_b, xbuf, xbuf, M, 768, 3072, 6, 3072, 768, 768,
        nullptr, nullptr, nullptr, 0, 1, 0);
  };

  // head block: only token 0 consumed downstream. gmode=1 fuses the b2 gather
  // into the LN read; resp/rstride select the proj residual source.
  auto apply_head_block = [&](const float* xsrc, const BlkP& p, int nb, int ntok_,
                              const float* ng, const float* nbias, int mode,
                              int gmode, const float* resp, int rstride) {
    const int M = nb * ntok_;
    const int gm = (M + 127) / 128;
    const int gm0 = (nb + 127) / 128;
    const int pad = (ntok_ == NTOK) ? 224 : 64;
    const int nr = gmode ? nb : 0;
    tln_kernel<<<dim3(6912 + (M + 3) / 4 + (nr + 3) / 4), blk, 0, stream>>>(
        p.qkv_w, p.proj_w, p.fc1_w, p.fc2_w, qkvT, projT, fc1T, fc2T,
        xsrc, p.ln1_g, p.ln1_b, hb, M, gmode, rcb, nr);
    gemm_db<false, false, bf16, 2><<<dim3(gm * 12), blk, 0, stream>>>(
        hb, qkvT + 768 * 768, p.qkv_b + 768, nullptr, (bf16*)nullptr,
        M, 1536, 768, 12, 768, 0, 0, qb, kb, vb, pad, ntok_, 768);
    gemm_db<false, false, bf16, 2><<<dim3(gm0 * 6), blk, 0, stream>>>(
        hb, qkvT, p.qkv_b, nullptr, (bf16*)nullptr,
        nb, 768, 768, 6, ntok_ * 768, 0, 0, qb, kb, vb, pad, 1, 0);
    vtrans_kernel<<<dim3(nb, NHEAD), blk, 0, stream>>>(vb, vTb, ntok_, pad);
    if (ntok_ == NTOK)
      attn_kernel<14, true><<<dim3(nb, NHEAD), blk, 0, stream>>>(qb, kb, vTb, ao, ntok_, pad);
    else
      attn_kernel<4, true><<<dim3(nb, NHEAD), blk, 0, stream>>>(qb, kb, vTb, ao, ntok_, pad);
    gemm_db<false, true, float, 0><<<dim3(gm0 * 6), blk, 0, stream>>>(
        ao, projT, p.proj_b, resp, y0, nb, 768, 768, 6, ntok_ * 768, rstride, 768,
        nullptr, nullptr, nullptr, 0, 1, 0);
    ln_kernel<<<dim3((nb + 3) / 4), blk, 0, stream>>>(y0, p.ln2_g, p.ln2_b, hb0, nb);
    gemm_db<true, false, bf16, 0><<<dim3(gm0 * 24), blk, 0, stream>>>(
        hb0, fc1T, p.fc1_b, nullptr, big0, nb, 3072, 768, 24, 768, 3072, 3072,
        nullptr, nullptr, nullptr, 0, 1, 0);
    gemm_db<false, true, float, 0><<<dim3(gm0 * 6), blk, 0, stream>>>(
        big0, fc2T, p.fc2_b, y0, f0b, nb, 768, 3072, 6, 3072, 768, 768,
        nullptr, nullptr, nullptr, 0, 1, 0);
    ln_head_kernel<<<dim3((nb + 3) / 4), blk, 0, stream>>>(
        f0b, 1, ng, nbias, out, nb, mode);
  };

  // 1) patch embed: im2col+cast -> GEMM(conv) -> assemble
  {
    int total = 13440 * 768 + 768 * 768;
    prep_kernel<<<dim3((total + 255) / 256), blk, 0, stream>>>(xin, big, convw, qkvT);
    gemm_db<false, false, bf16, 0><<<dim3(105 * 6), blk, 0, stream>>>(
        big, qkvT, convb, nullptr, ao, 13440, 768, 768, 6, 768, 768, 768,
        nullptr, nullptr, nullptr, 0, 1, 0);
    total = 13504 * 768;
    assemble_kernel<<<dim3((total + 255) / 256), blk, 0, stream>>>(ao, cls, pos, sie, cids, tA);
  }

  // 2) 11 stacked blocks (lead-dim DEPTH params)
  const float* bp[12];
  for (int i = 0; i < 12; ++i) bp[i] = (const float*)d_in[7 + i];
  for (int dd = 0; dd < DEPTH; ++dd) {
    BlkP p;
    p.ln1_g = bp[0] + dd * 768;                p.ln1_b = bp[1] + dd * 768;
    p.qkv_w = bp[2] + (size_t)dd * 768 * 2304; p.qkv_b = bp[3] + dd * 2304;
    p.proj_w = bp[4] + (size_t)dd * 768 * 768; p.proj_b = bp[5] + dd * 768;
    p.ln2_g = bp[6] + dd * 768;                p.ln2_b = bp[7] + dd * 768;
    p.fc1_w = bp[8] + (size_t)dd * 768 * 3072; p.fc1_b = bp[9] + dd * 3072;
    p.fc2_w = bp[10] + (size_t)dd * 3072 * 768; p.fc2_b = bp[11] + dd * 768;
    apply_block(tA, p, 64, NTOK);
  }

  // 3) b1 branch: f0 = LN(block(t))[:,0]  (token-0 head path; res = tA strided)
  {
    BlkP p;
    p.ln1_g = (const float*)d_in[19]; p.ln1_b = (const float*)d_in[20];
    p.qkv_w = (const float*)d_in[21]; p.qkv_b = (const float*)d_in[22];
    p.proj_w = (const float*)d_in[23]; p.proj_b = (const float*)d_in[24];
    p.ln2_g = (const float*)d_in[25]; p.ln2_b = (const float*)d_in[26];
    p.fc1_w = (const float*)d_in[27]; p.fc1_b = (const float*)d_in[28];
    p.fc2_w = (const float*)d_in[29]; p.fc2_b = (const float*)d_in[30];
    apply_head_block(tA, p, 64, NTOK,
                     (const float*)d_in[31], (const float*)d_in[32], 0,
                     0, tA, NTOK * 768);
  }

  // 4) b2 branch: gather fused into tln (gmode=1); res = rcb (cls rows copy)
  {
    BlkP p;
    p.ln1_g = (const float*)d_in[33]; p.ln1_b = (const float*)d_in[34];
    p.qkv_w = (const float*)d_in[35]; p.qkv_b = (const float*)d_in[36];
    p.proj_w = (const float*)d_in[37]; p.proj_b = (const float*)d_in[38];
    p.ln2_g = (const float*)d_in[39]; p.ln2_b = (const float*)d_in[40];
    p.fc1_w = (const float*)d_in[41]; p.fc1_b = (const float*)d_in[42];
    p.fc2_w = (const float*)d_in[43]; p.fc2_b = (const float*)d_in[44];
    apply_head_block(tA, p, 256, 53,
                     (const float*)d_in[45], (const float*)d_in[46], 1,
                     1, rcb, 768);
  }
}